// Round 1
// baseline (1325.906 us; speedup 1.0000x reference)
//
#include <hip/hip_runtime.h>
#include <hip/hip_bf16.h>

// Flash-attention fwd with additive bias, fp32 in/out, bf16 MFMA compute.
// B=4 S=2048 H=12 D=64; bias [b,h,sq,sk] is 805 MB -> HBM-bound on bias stream.
#define B_ 4
#define S_ 2048
#define H_ 12
#define D_ 64
#define QT 64
#define KT 64
#define NQT (S_/QT)   // 32
#define NKT (S_/KT)   // 32
#define LOG2E 1.44269504088896340736f

typedef __bf16 bf16x8 __attribute__((ext_vector_type(8)));
typedef __bf16 bf16x4 __attribute__((ext_vector_type(4)));
typedef float  f32x4  __attribute__((ext_vector_type(4)));

// MFMA 16x16x32 bf16 layouts (learn_hip m89/m91/m120 verified):
//   A[m=lane&15][k=(lane>>4)*8+j]   B[k=(lane>>4)*8+j][n=lane&15]
//   C/D: col=lane&15, row=(lane>>4)*4+reg
__global__ __launch_bounds__(256, 2) void fa_fwd(
    const float* __restrict__ Q, const float* __restrict__ K,
    const float* __restrict__ V, const float* __restrict__ Bias,
    float* __restrict__ Out)
{
  // stride 72 (bf16): 144 B rows -> 16B-aligned b128 frag reads, 2-way banks.
  // Vt stride 68: 136 B rows -> 8B-aligned b64 pair reads, ~4-way banks.
  __shared__ __attribute__((aligned(16))) __bf16 Qs[QT*72];
  __shared__ __attribute__((aligned(16))) __bf16 Ks[KT*72];
  __shared__ __attribute__((aligned(16))) __bf16 Vt[D_*68];
  __shared__ __attribute__((aligned(16))) __bf16 Ps[4*16*72];

  const int bid = blockIdx.x;
  const int qt  = bid & (NQT-1);
  const int bh  = bid >> 5;          // log2(NQT)
  const int b   = bh / H_;
  const int h   = bh - b*H_;
  const int q0  = qt*QT;

  const int tid  = threadIdx.x;
  const int w    = tid >> 6;         // wave 0..3 -> q rows 16w..16w+15
  const int lane = tid & 63;
  const int g    = lane >> 4;        // quad
  const int c    = lane & 15;

  const float qscale = 0.125f * LOG2E;  // fold softmax scale + base-2 into Q

  // ---- load Q tile once (pre-scaled, bf16) ----
  #pragma unroll
  for (int i = 0; i < 4; ++i) {
    int flat = i*256 + tid;
    int qr = flat >> 4;
    int d4 = (flat & 15) << 2;
    float4 qv = *(const float4*)(Q + (((size_t)b*S_ + q0 + qr)*H_ + h)*D_ + d4);
    bf16x4 pk;
    pk[0] = (__bf16)(qv.x * qscale); pk[1] = (__bf16)(qv.y * qscale);
    pk[2] = (__bf16)(qv.z * qscale); pk[3] = (__bf16)(qv.w * qscale);
    *(bf16x4*)&Qs[qr*72 + d4] = pk;
  }

  f32x4 Ov[4] = {};                 // O accumulator, C-layout, 4 d-subtiles
  float m_i[4], l_i[4];
  #pragma unroll
  for (int r = 0; r < 4; ++r) { m_i[r] = -1e30f; l_i[r] = 0.f; }

  const size_t row_base = (size_t)q0 + 16*w + 4*g;
  const float* bb    = Bias + ((size_t)bh*S_ + row_base)*S_ + c;
  const float* kbase = K + ((size_t)b*S_*H_ + h)*D_;
  const float* vbase = V + ((size_t)b*S_*H_ + h)*D_;

  for (int kt = 0; kt < NKT; ++kt) {
    const int k0 = kt*KT;

    // issue bias loads for this tile early (C-layout: 16 dwords/lane,
    // 64B-contiguous per 16-lane group; block consumes full 256B rows)
    float bl[4][4];
    #pragma unroll
    for (int t = 0; t < 4; ++t)
      #pragma unroll
      for (int r = 0; r < 4; ++r)
        bl[t][r] = bb[(size_t)r*S_ + k0 + 16*t];

    __syncthreads();  // previous iteration's frag reads done before overwrite

    // stage K tile [key][d] bf16
    #pragma unroll
    for (int i = 0; i < 4; ++i) {
      int flat = i*256 + tid;
      int kr = flat >> 4;
      int d4 = (flat & 15) << 2;
      float4 kv = *(const float4*)(kbase + (size_t)(k0+kr)*H_*D_ + d4);
      bf16x4 pk;
      pk[0]=(__bf16)kv.x; pk[1]=(__bf16)kv.y; pk[2]=(__bf16)kv.z; pk[3]=(__bf16)kv.w;
      *(bf16x4*)&Ks[kr*72 + d4] = pk;
    }
    // stage V tile transposed: Vt[d][key] (PV B-frag wants keys contiguous)
    #pragma unroll
    for (int i = 0; i < 4; ++i) {
      int flat = i*256 + tid;
      int vr = flat >> 4;
      int d4 = (flat & 15) << 2;
      float4 vv = *(const float4*)(vbase + (size_t)(k0+vr)*H_*D_ + d4);
      Vt[(d4+0)*68 + vr] = (__bf16)vv.x;
      Vt[(d4+1)*68 + vr] = (__bf16)vv.y;
      Vt[(d4+2)*68 + vr] = (__bf16)vv.z;
      Vt[(d4+3)*68 + vr] = (__bf16)vv.w;
    }
    __syncthreads();

    // ---- S = Q*K^T (scaled,base2) + bias*log2e ----
    bf16x8 aq0 = *(const bf16x8*)&Qs[(16*w + c)*72 + 8*g];
    bf16x8 aq1 = *(const bf16x8*)&Qs[(16*w + c)*72 + 32 + 8*g];
    float sc[4][4];
    #pragma unroll
    for (int t = 0; t < 4; ++t) {
      bf16x8 bk0 = *(const bf16x8*)&Ks[(16*t + c)*72 + 8*g];
      bf16x8 bk1 = *(const bf16x8*)&Ks[(16*t + c)*72 + 32 + 8*g];
      f32x4 acc = {};
      acc = __builtin_amdgcn_mfma_f32_16x16x32_bf16(aq0, bk0, acc, 0, 0, 0);
      acc = __builtin_amdgcn_mfma_f32_16x16x32_bf16(aq1, bk1, acc, 0, 0, 0);
      #pragma unroll
      for (int r = 0; r < 4; ++r)
        sc[t][r] = acc[r] + bl[t][r] * LOG2E;
    }

    // ---- online softmax (rows 4g+r; reduce over cols = 16-lane group) ----
    #pragma unroll
    for (int r = 0; r < 4; ++r) {
      float mv = fmaxf(fmaxf(sc[0][r], sc[1][r]), fmaxf(sc[2][r], sc[3][r]));
      #pragma unroll
      for (int mask = 1; mask <= 8; mask <<= 1)
        mv = fmaxf(mv, __shfl_xor(mv, mask, 64));
      float mn = fmaxf(m_i[r], mv);
      float alpha = __builtin_amdgcn_exp2f(m_i[r] - mn);
      m_i[r] = mn;
      float rs = 0.f;
      #pragma unroll
      for (int t = 0; t < 4; ++t) {
        float p = __builtin_amdgcn_exp2f(sc[t][r] - mn);
        sc[t][r] = p;
        rs += p;
      }
      #pragma unroll
      for (int mask = 1; mask <= 8; mask <<= 1)
        rs += __shfl_xor(rs, mask, 64);
      l_i[r] = l_i[r]*alpha + rs;
      #pragma unroll
      for (int t = 0; t < 4; ++t)
        Ov[t][r] *= alpha;
    }

    // ---- P: C-layout -> A-layout via per-wave-private LDS ----
    #pragma unroll
    for (int t = 0; t < 4; ++t)
      #pragma unroll
      for (int r = 0; r < 4; ++r)
        Ps[w*1152 + (4*g + r)*72 + 16*t + c] = (__bf16)sc[t][r];
    // (same-wave LDS RAW: compiler inserts lgkmcnt; no block barrier needed)

    // ---- O += P*V ----
    #pragma unroll
    for (int hh = 0; hh < 2; ++hh) {
      bf16x8 ap = *(const bf16x8*)&Ps[w*1152 + c*72 + 32*hh + 8*g];
      #pragma unroll
      for (int t = 0; t < 4; ++t) {
        union { bf16x8 v8; bf16x4 v4[2]; } bv;
        bv.v4[0] = *(const bf16x4*)&Vt[(16*t + c)*68 + 32*hh + 8*g];
        bv.v4[1] = *(const bf16x4*)&Vt[(16*t + c)*68 + 32*hh + 8*g + 4];
        Ov[t] = __builtin_amdgcn_mfma_f32_16x16x32_bf16(ap, bv.v8, Ov[t], 0, 0, 0);
      }
    }
  }

  // ---- epilogue: O / l, write [b, q, h, d] fp32 ----
  float* ob = Out + (((size_t)b*S_ + row_base)*H_ + h)*D_ + c;
  #pragma unroll
  for (int r = 0; r < 4; ++r) {
    float inv = 1.0f / l_i[r];
    #pragma unroll
    for (int t = 0; t < 4; ++t)
      ob[(size_t)r*H_*D_ + 16*t] = Ov[t][r] * inv;
  }
}

extern "C" void kernel_launch(void* const* d_in, const int* in_sizes, int n_in,
                              void* d_out, int out_size, void* d_ws, size_t ws_size,
                              hipStream_t stream) {
  const float* q    = (const float*)d_in[0];
  const float* k    = (const float*)d_in[1];
  const float* v    = (const float*)d_in[2];
  const float* bias = (const float*)d_in[3];
  float* out = (float*)d_out;
  dim3 grid(B_ * H_ * NQT);   // 1536 blocks
  fa_fwd<<<grid, 256, 0, stream>>>(q, k, v, bias, out);
}